// Round 12
// baseline (102.046 us; speedup 1.0000x reference)
//
#include <hip/hip_runtime.h>

// Problem constants (fixed by reference)
constexpr int B = 4, T = 8, V = 256, F = 64;
constexpr int BT = B * T;            // 32 (b,t) slices
constexpr int CHUNK = 8;             // rows of i per block (proven sweet spot)
constexpr int NCHUNK = V / CHUNK;    // 32 -> 1024 logical blocks
constexpr int NXCD = 8;
constexpr int REP = 4;               // R17: x4 replication (diagnostic)

typedef float v2f __attribute__((ext_vector_type(2)));

// R17 — CLEAN DIAGNOSTIC (intentional ~4x kernel time; revert next round).
// R16 (whole-column batch preload) was neutral -> cold-chain theory dead.
// Matrix complete: coalescing/TLP/ILP/LDS/SMEM/XCD/fetch/BW/write-allocate
// all falsified; kernel ~24us in EVERY structure. Last unknown: R12 hinted
// VALU issue time/wave ~6x the source estimate (VALUBusy 17% @1 wave/SIMD)
// but R12's opaque-asm diagnostic perturbed codegen (VGPR 100->256).
// This round: BIT-IDENTICAL R10 body (best, 71.85us), replicated by GRID
// (logical = blockIdx.x & 1023, replica = >>10; replicas write identical
// values -> idempotent, absmax 0). Body codegen untouched -> the top-5 row
// finally shows the REAL kernel's VALUBusy/VGPR/FETCH.
// Decision: VALUBusy>=60% -> VALU-issue-bound, attack instr count (asm
// v_pk). VALUBusy<=30% @ ~4 blk/CU occupancy -> declare practical roofline
// (41 fill + 7 graph + 24 kernel).
__global__ __launch_bounds__(256)
void gl_fused(const float* __restrict__ X, const float* __restrict__ A,
              float* __restrict__ OUT)
{
    const int tid = threadIdx.x;           // column j
    const int lblk = blockIdx.x & (BT * NCHUNK - 1);   // logical block (replica-folded)
    // XCD swizzle: consecutive logical blocks (same bt) pinned to one XCD
    const int lb  = (lblk & (NXCD - 1)) * (BT * NCHUNK / NXCD)
                  + (lblk >> 3);
    const int bt  = lb >> 5;               // / NCHUNK
    const int ic  = lb & (NCHUNK - 1);
    const int i0  = ic * CHUNK;

    const float* xbt = X + (size_t)bt * V * F;            // [256][64] tile
    const float4* xrow4 = reinterpret_cast<const float4*>(xbt + (size_t)i0 * F);
    // xrow4[r*(F/4) + k] = float4 of row i0+r, features 4k..4k+3 (uniform addr)

    __shared__ float wpart[4][CHUNK];      // per-wave partial row sums
    __shared__ float rden[CHUNK];          // reciprocal denominators

    // a -> uniform address, scalarized; keep as packed pairs
    v2f af2[F / 2];
#pragma unroll
    for (int k = 0; k < F / 4; ++k) {
        const float4 v = reinterpret_cast<const float4*>(A)[k];
        af2[2*k+0] = (v2f){v.x, v.y};
        af2[2*k+1] = (v2f){v.z, v.w};
    }

    v2f acc2[CHUNK];
#pragma unroll
    for (int r = 0; r < CHUNK; ++r) acc2[r] = (v2f){0.0f, 0.0f};

    // stream own column in float4 chunks; CHUNK independent packed fma chains.
    const float4* colp = reinterpret_cast<const float4*>(xbt + (size_t)tid * F);
#pragma unroll
    for (int k = 0; k < F / 4; ++k) {
        const float4 xv = colp[k];
        const v2f xlo = (v2f){xv.x, xv.y};
        const v2f xhi = (v2f){xv.z, xv.w};
#pragma unroll
        for (int r = 0; r < CHUNK; ++r) {
            const float4 sr = xrow4[r * (F / 4) + k];   // uniform -> s_load_dwordx4
            const v2f d0 = xlo - (v2f){sr.x, sr.y};     // v_pk_add (neg mod)
            const v2f d1 = xhi - (v2f){sr.z, sr.w};
            const v2f a0 = __builtin_elementwise_max(d0, -d0);  // v_pk_max (neg mod)
            const v2f a1 = __builtin_elementwise_max(d1, -d1);
            acc2[r] = __builtin_elementwise_fma(a0, af2[2*k+0], acc2[r]); // v_pk_fma
            acc2[r] = __builtin_elementwise_fma(a1, af2[2*k+1], acc2[r]);
        }
    }

    float tmp[CHUNK];
#pragma unroll
    for (int r = 0; r < CHUNK; ++r) {
        const float s = acc2[r].x + acc2[r].y;
        tmp[r] = __expf(fmaxf(s, 0.0f));
    }

    // block reduction: row sum = denominator (symmetry)
    const int lane = tid & 63;
    const int wv   = tid >> 6;
#pragma unroll
    for (int r = 0; r < CHUNK; ++r) {
        float v = tmp[r];
        v += __shfl_xor(v, 32);
        v += __shfl_xor(v, 16);
        v += __shfl_xor(v, 8);
        v += __shfl_xor(v, 4);
        v += __shfl_xor(v, 2);
        v += __shfl_xor(v, 1);
        if (lane == 0) wpart[wv][r] = v;
    }
    __syncthreads();
    if (tid < CHUNK) {
        const float d = wpart[0][tid] + wpart[1][tid] + wpart[2][tid] + wpart[3][tid];
        rden[tid] = 1.0f / d;
    }
    __syncthreads();

    // S[bt, i0+r, tid] = tmp[r] / denom[i0+r]; consecutive tids -> coalesced
    float* obase = OUT + (((size_t)bt * V + i0) * V) + tid;
#pragma unroll
    for (int r = 0; r < CHUNK; ++r)
        obase[(size_t)r * V] = tmp[r] * rden[r];
}

extern "C" void kernel_launch(void* const* d_in, const int* in_sizes, int n_in,
                              void* d_out, int out_size, void* d_ws, size_t ws_size,
                              hipStream_t stream)
{
    const float* X = (const float*)d_in[0];   // [B,T,V,F] fp32
    const float* A = (const float*)d_in[1];   // [F,1]     fp32
    float* OUT = (float*)d_out;               // [B,T,V,V] fp32

    dim3 grid(BT * NCHUNK * REP), block(256);
    gl_fused<<<grid, block, 0, stream>>>(X, A, OUT);
}

// Round 13
// 73.023 us; speedup vs baseline: 1.3974x; 1.3974x over previous
//
#include <hip/hip_runtime.h>

// Problem constants (fixed by reference)
constexpr int B = 4, T = 8, V = 256, F = 64;
constexpr int BT = B * T;            // 32 (b,t) slices
constexpr int CHUNK = 4;             // R18: 2048 blocks -> 8 blocks/CU capacity
constexpr int NCHUNK = V / CHUNK;    // 64
constexpr int NXCD = 8;
constexpr int K4 = F / 4;            // 16 float4 chunks per row

typedef float v2f __attribute__((ext_vector_type(2)));

// R18 — attack the MEASURED bottleneck (R17 diagnostic, real-body counters):
//   VALUBusy=73% @ full occupancy, VGPR=64, FETCH=1.25MB, HBM 177GB/s
//   -> VALU-ISSUE-BOUND. ~3000 VALU instr/wave measured vs ~1100 ideal:
//   bloat = SGPR->VGPR v_mov unpacking of the s_load row data (the
//   (v2f){sr.x,sr.y} construction materializes SGPRs into VGPRs, ~512+
//   movs/thread) since VOP3P sources weren't encoded as SGPR pairs.
//   Fix (a): inline-asm v_pk_add_f32 with the row operand via "s"
//   constraint = SGPR pair read directly, ZERO movs. d = s + (-x) with
//   -x negated once per k (no asm modifiers needed); |d| identical.
//   Fix (b): scalar fmaf with 'a' as SGPR scalars (1 SGPR/instr rule ok)
//   -> af2's 32 VGPRs freed; 4 independent acc chains per row.
//   Fix (c): CHUNK=4 -> 2048 blocks; at <=64 VGPR that's 8 blocks/CU
//   = 8 waves/SIMD (R13 tested this only under bloated codegen where
//   the issue port was saturated; now the extra waves can fill latency).
// Two-point model (R10 24us = ramp + s; R17 54.4 = ramp + 4s): steady
//   s ~= 10us is issue-time ✓, ramp ~= 14us is the remaining latency term.
// Falsified: coalescing(R7) forced-occupancy(R8) LDS-rows(R9/R11)
//   XCD(R10,kept) overfetch/BW/writealloc(R12) TLP@bloat(R13) ILP(R14)
//   SMEM-drain(R15) cold-chain(R16).
__global__ __launch_bounds__(256)
void gl_fused(const float* __restrict__ X, const float* __restrict__ A,
              float* __restrict__ OUT)
{
    const int tid = threadIdx.x;           // column j
    // XCD swizzle (bijective: 2048 = 8*256)
    const int lb  = (blockIdx.x & (NXCD - 1)) * (BT * NCHUNK / NXCD)
                  + (blockIdx.x >> 3);
    const int bt  = lb >> 6;               // / NCHUNK (=64)
    const int ic  = lb & (NCHUNK - 1);
    const int i0  = ic * CHUNK;

    const float* xbt = X + (size_t)bt * V * F;            // [256][64] tile
    const float4* xrow4 = reinterpret_cast<const float4*>(xbt + (size_t)i0 * F);
    const float4* a4    = reinterpret_cast<const float4*>(A);   // uniform->SGPR

    __shared__ float wpart[4][CHUNK];      // per-wave partial row sums
    __shared__ float rden[CHUNK];          // reciprocal denominators

    float acc[CHUNK][4];                   // 16 VGPR, 16 independent fma chains
#pragma unroll
    for (int r = 0; r < CHUNK; ++r)
#pragma unroll
        for (int c = 0; c < 4; ++c) acc[r][c] = 0.0f;

    const float4* colp = reinterpret_cast<const float4*>(xbt + (size_t)tid * F);
#pragma unroll 4
    for (int k = 0; k < K4; ++k) {
        const float4 xv = colp[k];
        const float4 av = a4[k];           // uniform, loop-inv -> SGPR scalars
        // negate col once per k so the pk_add needs no modifiers:
        // d = s + (-x);  |d| == |x - s|
        v2f nxlo = (v2f){-xv.x, -xv.y};
        v2f nxhi = (v2f){-xv.z, -xv.w};
#pragma unroll
        for (int r = 0; r < CHUNK; ++r) {
            const float4 sr = xrow4[r * K4 + k];   // uniform -> s_load_dwordx4
            unsigned long long s01, s23;           // keep as SGPR pairs
            {
                float2 t0 = make_float2(sr.x, sr.y);
                float2 t1 = make_float2(sr.z, sr.w);
                __builtin_memcpy(&s01, &t0, 8);
                __builtin_memcpy(&s23, &t1, 8);
            }
            v2f d01, d23;
            // VOP3P src0 = SGPR pair (1 scalar read), src1 = VGPR pair.
            asm("v_pk_add_f32 %0, %1, %2" : "=v"(d01) : "s"(s01), "v"(nxlo));
            asm("v_pk_add_f32 %0, %1, %2" : "=v"(d23) : "s"(s23), "v"(nxhi));
            // |d| = v_max_f32 v,v,-v (neg modifier); fma with SGPR a scalar.
            acc[r][0] = fmaf(fmaxf(d01.x, -d01.x), av.x, acc[r][0]);
            acc[r][1] = fmaf(fmaxf(d01.y, -d01.y), av.y, acc[r][1]);
            acc[r][2] = fmaf(fmaxf(d23.x, -d23.x), av.z, acc[r][2]);
            acc[r][3] = fmaf(fmaxf(d23.y, -d23.y), av.w, acc[r][3]);
        }
    }

    float tmp[CHUNK];
#pragma unroll
    for (int r = 0; r < CHUNK; ++r) {
        const float s = (acc[r][0] + acc[r][1]) + (acc[r][2] + acc[r][3]);
        tmp[r] = __expf(fmaxf(s, 0.0f));
    }

    // block reduction: row sum = denominator (symmetry)
    const int lane = tid & 63;
    const int wv   = tid >> 6;
#pragma unroll
    for (int r = 0; r < CHUNK; ++r) {
        float v = tmp[r];
        v += __shfl_xor(v, 32);
        v += __shfl_xor(v, 16);
        v += __shfl_xor(v, 8);
        v += __shfl_xor(v, 4);
        v += __shfl_xor(v, 2);
        v += __shfl_xor(v, 1);
        if (lane == 0) wpart[wv][r] = v;
    }
    __syncthreads();
    if (tid < CHUNK) {
        const float d = wpart[0][tid] + wpart[1][tid] + wpart[2][tid] + wpart[3][tid];
        rden[tid] = 1.0f / d;
    }
    __syncthreads();

    // S[bt, i0+r, tid] = tmp[r] / denom[i0+r]; consecutive tids -> coalesced
    float* obase = OUT + (((size_t)bt * V + i0) * V) + tid;
#pragma unroll
    for (int r = 0; r < CHUNK; ++r)
        obase[(size_t)r * V] = tmp[r] * rden[r];
}

extern "C" void kernel_launch(void* const* d_in, const int* in_sizes, int n_in,
                              void* d_out, int out_size, void* d_ws, size_t ws_size,
                              hipStream_t stream)
{
    const float* X = (const float*)d_in[0];   // [B,T,V,F] fp32
    const float* A = (const float*)d_in[1];   // [F,1]     fp32
    float* OUT = (float*)d_out;               // [B,T,V,V] fp32

    dim3 grid(BT * NCHUNK), block(256);
    gl_fused<<<grid, block, 0, stream>>>(X, A, OUT);
}